// Round 1
// baseline (366.982 us; speedup 1.0000x reference)
//
#include <hip/hip_runtime.h>
#include <math.h>

// NoisyTopkRouter: B=8,T=4096,NE=1024,E=16,TOPK=2,LIN=1824
// tokens = 32768; per-token streamed features = 1792 (city 32 handled as constant)
// out = [router 32768*16][indices 32768*2][gate1 32768*16] all as f32

#define TOK_PER_BLOCK 64
#define CHUNKS_PER_WAVE 7   // 7 chunks * 64 k = 448 k per wave; 4 waves = 1792
#define I_OFF 524288        // 32768*16
#define G_OFF 589824        // 524288 + 32768*2

__device__ __forceinline__ float softplus_f(float x) {
  // jax.nn.softplus = logaddexp(x,0) = max(x,0) + log1p(exp(-|x|))
  return fmaxf(x, 0.0f) + log1pf(expf(-fabsf(x)));
}

__device__ __forceinline__ float get_comp(const float4& v, int kk) {
  return kk == 0 ? v.x : kk == 1 ? v.y : kk == 2 ? v.z : v.w;
}

#define DO_FMA(AV, J)                               \
  {                                                 \
    float s_ = (AV);                                \
    accL[J].x = fmaf(s_, wl.x, accL[J].x);          \
    accL[J].y = fmaf(s_, wl.y, accL[J].y);          \
    accL[J].z = fmaf(s_, wl.z, accL[J].z);          \
    accL[J].w = fmaf(s_, wl.w, accL[J].w);          \
    accH[J].x = fmaf(s_, wh.x, accH[J].x);          \
    accH[J].y = fmaf(s_, wh.y, accH[J].y);          \
    accH[J].z = fmaf(s_, wh.z, accH[J].z);          \
    accH[J].w = fmaf(s_, wh.w, accH[J].w);          \
  }

__global__ __launch_bounds__(256, 2) void router_kernel(
    const float* __restrict__ mh, const float* __restrict__ dt,
    const float* __restrict__ dd, const float* __restrict__ rg,
    const float* __restrict__ de, const float* __restrict__ cemb_all,
    const float* __restrict__ w_route, const float* __restrict__ b_route,
    const float* __restrict__ w_noise, const float* __restrict__ b_noise,
    const float* __restrict__ eps, const int* __restrict__ city_index,
    float* __restrict__ out) {
  // union: W chunks [4 waves][64 k][32 e] = 8192 floats  /  score [64 tok][132]
  __shared__ float smem[8448];
  __shared__ float city_l[32];  // bias + city-embed contribution per e-col

  const int tid = threadIdx.x;
  const int w   = tid >> 6;   // wave 0..3 (k-split)
  const int ln  = tid & 63;
  const int tg  = ln & 15;    // token group: tokens tg*4..tg*4+3
  const int eg  = ln >> 4;    // e group: cols eg*8..eg*8+7 (of 32 = route|noise)
  const int blockTok = blockIdx.x * TOK_PER_BLOCK;

  // ---- constant term: bias + city_embed . W[1024:1056] (done once, tiny) ----
  if (tid < 32) {
    const int e = tid & 15;
    const float* wsrc = (tid < 16) ? w_route : w_noise;
    const float* bsrc = (tid < 16) ? b_route : b_noise;
    const float* ce = cemb_all + city_index[0] * 32;
    float s = bsrc[e];
#pragma unroll
    for (int j = 0; j < 32; ++j) s = fmaf(ce[j], wsrc[(1024 + j) * 16 + e], s);
    city_l[tid] = s;
  }

  float4 accL[4], accH[4];
#pragma unroll
  for (int j = 0; j < 4; ++j) {
    accL[j] = make_float4(0.f, 0.f, 0.f, 0.f);
    accH[j] = make_float4(0.f, 0.f, 0.f, 0.f);
  }

  const int gbase = w * CHUNKS_PER_WAVE;
  float4 wreg[8];  // next W chunk in registers (global->reg prefetch)

  auto load_wchunk = [&](int g, float4* r) {
    // global feature k -> weight row: skip rows 1024..1055 (city)
    const int krow_base = g * 64 + ((g * 64 >= 1024) ? 32 : 0);
#pragma unroll
    for (int rr = 0; rr < 8; ++rr) {
      int idx = rr * 64 + ln;
      int row = idx >> 3, c4 = idx & 7;
      const float* src = (c4 < 4)
          ? (w_route + (krow_base + row) * 16 + c4 * 4)
          : (w_noise + (krow_base + row) * 16 + (c4 - 4) * 4);
      r[rr] = *(const float4*)src;
    }
  };

  load_wchunk(gbase, wreg);

  float* WL = &smem[w * 2048];          // wave-private W chunk [64][32]
  const float* WLr = WL + eg * 8;       // this lane's e-slice base

  for (int c = 0; c < CHUNKS_PER_WAVE; ++c) {
    const int g = gbase + c;

    __syncthreads();  // previous compute done -> W buffer free
#pragma unroll
    for (int rr = 0; rr < 8; ++rr) {
      int idx = rr * 64 + ln;
      int row = idx >> 3, c4 = idx & 7;
      *(float4*)&WL[row * 32 + c4 * 4] = wreg[rr];
    }
    __syncthreads();  // W chunk visible

    if (c + 1 < CHUNKS_PER_WAVE) load_wchunk(g + 1, wreg);  // in flight over compute

    // A source array for this 64-k chunk (boundaries all multiples of 64)
    const float* base; int stride;
    if (g < 16)      { base = mh + g * 64;        stride = 1024; }
    else if (g < 20) { base = dt + (g - 16) * 64; stride = 256; }
    else if (g < 24) { base = dd + (g - 20) * 64; stride = 256; }
    else if (g < 26) { base = rg + (g - 24) * 64; stride = 128; }
    else             { base = de + (g - 26) * 64; stride = 128; }

    const int t0 = blockTok + tg * 4;
    const float* A0 = base + (size_t)(t0 + 0) * stride;
    const float* A1 = base + (size_t)(t0 + 1) * stride;
    const float* A2 = base + (size_t)(t0 + 2) * stride;
    const float* A3 = base + (size_t)(t0 + 3) * stride;

#pragma unroll 4
    for (int q = 0; q < 16; ++q) {
      float4 a0 = *(const float4*)(A0 + q * 4);
      float4 a1 = *(const float4*)(A1 + q * 4);
      float4 a2 = *(const float4*)(A2 + q * 4);
      float4 a3 = *(const float4*)(A3 + q * 4);
#pragma unroll
      for (int kk = 0; kk < 4; ++kk) {
        const int k = q * 4 + kk;
        float4 wl = *(const float4*)(WLr + k * 32);      // broadcast, conflict-free
        float4 wh = *(const float4*)(WLr + k * 32 + 4);
        DO_FMA(get_comp(a0, kk), 0);
        DO_FMA(get_comp(a1, kk), 1);
        DO_FMA(get_comp(a2, kk), 2);
        DO_FMA(get_comp(a3, kk), 3);
      }
    }
  }

  // ---- split-K reduction through LDS ----
  __syncthreads();  // all waves done with W buffer; smem becomes score[64][132]
#pragma unroll
  for (int j = 0; j < 4; ++j) {
    float* srow = &smem[(tg * 4 + j) * 132 + w * 32 + eg * 8];
    *(float4*)(srow)     = accL[j];
    *(float4*)(srow + 4) = accH[j];
  }
  __syncthreads();

  // ---- epilogue: one lane per token (wave 0) ----
  if (tid < 64) {
    const int tokg = blockTok + tid;
    float l[32];
#pragma unroll
    for (int e4 = 0; e4 < 8; ++e4) {
      float4 s0 = *(const float4*)&smem[tid * 132 + 0 * 32 + e4 * 4];
      float4 s1 = *(const float4*)&smem[tid * 132 + 1 * 32 + e4 * 4];
      float4 s2 = *(const float4*)&smem[tid * 132 + 2 * 32 + e4 * 4];
      float4 s3 = *(const float4*)&smem[tid * 132 + 3 * 32 + e4 * 4];
      l[e4 * 4 + 0] = s0.x + s1.x + s2.x + s3.x + city_l[e4 * 4 + 0];
      l[e4 * 4 + 1] = s0.y + s1.y + s2.y + s3.y + city_l[e4 * 4 + 1];
      l[e4 * 4 + 2] = s0.z + s1.z + s2.z + s3.z + city_l[e4 * 4 + 2];
      l[e4 * 4 + 3] = s0.w + s1.w + s2.w + s3.w + city_l[e4 * 4 + 3];
    }

    const float* ep = eps + (size_t)tokg * 16;
    float n[16];
#pragma unroll
    for (int e = 0; e < 16; ++e)
      n[e] = fmaf(ep[e], softplus_f(l[16 + e]), l[e]);  // noisy logits

    // top-2, lowest-index tie-break (matches lax.top_k)
    float m1 = -INFINITY; int i1 = 0;
#pragma unroll
    for (int e = 0; e < 16; ++e)
      if (n[e] > m1) { m1 = n[e]; i1 = e; }
    float m2 = -INFINITY; int i2 = 0;
#pragma unroll
    for (int e = 0; e < 16; ++e)
      if (e != i1 && n[e] > m2) { m2 = n[e]; i2 = e; }

    float ex[16], Z = 0.f;
#pragma unroll
    for (int e = 0; e < 16; ++e) { ex[e] = expf(n[e] - m1); Z += ex[e]; }
    const float invZ  = 1.0f / Z;
    const float invZ2 = 1.0f / (1.0f + expf(m2 - m1));  // ex[i1]=1

    float r[16], g1[16];
#pragma unroll
    for (int e = 0; e < 16; ++e) {
      r[e]  = (e == i1 || e == i2) ? ex[e] * invZ2 : 0.0f;
      g1[e] = ex[e] * invZ;
    }

    float* ro = out + (size_t)tokg * 16;
#pragma unroll
    for (int e4 = 0; e4 < 4; ++e4)
      *(float4*)(ro + e4 * 4) = make_float4(r[e4 * 4], r[e4 * 4 + 1], r[e4 * 4 + 2], r[e4 * 4 + 3]);

    out[I_OFF + (size_t)tokg * 2 + 0] = (float)i1;
    out[I_OFF + (size_t)tokg * 2 + 1] = (float)i2;

    float* go = out + G_OFF + (size_t)tokg * 16;
#pragma unroll
    for (int e4 = 0; e4 < 4; ++e4)
      *(float4*)(go + e4 * 4) = make_float4(g1[e4 * 4], g1[e4 * 4 + 1], g1[e4 * 4 + 2], g1[e4 * 4 + 3]);
  }
}

extern "C" void kernel_launch(void* const* d_in, const int* in_sizes, int n_in,
                              void* d_out, int out_size, void* d_ws, size_t ws_size,
                              hipStream_t stream) {
  const float* mh = (const float*)d_in[0];   // [8,4096,1024]
  const float* dt = (const float*)d_in[1];   // [8,4096,256]
  const float* dd = (const float*)d_in[2];   // [8,4096,256]
  const float* rg = (const float*)d_in[3];   // [8,4096,128]
  const float* de = (const float*)d_in[4];   // [8,4096,128]
  const float* ce = (const float*)d_in[5];   // [4,32]
  const float* wr = (const float*)d_in[6];   // [1824,16]
  const float* br = (const float*)d_in[7];   // [16]
  const float* wn = (const float*)d_in[8];   // [1824,16]
  const float* bn = (const float*)d_in[9];   // [16]
  const float* ep = (const float*)d_in[10];  // [8,4096,16]
  const int*   ci = (const int*)d_in[11];    // scalar
  float* out = (float*)d_out;

  router_kernel<<<512, 256, 0, stream>>>(mh, dt, dd, rg, de, ce, wr, br, wn, bn,
                                         ep, ci, out);
}

// Round 2
// 304.196 us; speedup vs baseline: 1.2064x; 1.2064x over previous
//
#include <hip/hip_runtime.h>
#include <math.h>

// NoisyTopkRouter: B=8,T=4096,NE=1024,E=16,TOPK=2,LIN=1824
// tokens = 32768; streamed features = 1792 (city-32 folded into a constant)
// out = [router 32768*16][indices 32768*2][gate1 32768*16] all f32
//
// R2 structure: 32 tokens/block, grid 1024 (4 blocks/CU all-resident).
// Per 64-k chunk: A tile [32][64] + W chunk [64][32] staged in LDS, shared by
// all 4 waves; waves split the chunk's k into quarters (split-K, LDS-reduced).
// Next chunk prefetched into named scalar regs (no arrays -> no scratch spill).

#define TOKS 32
#define NCHUNK 28
#define I_OFF 524288        // 32768*16
#define G_OFF 589824        // 524288 + 32768*2

#define SA_STRIDE 68        // pad 64->68: token-row bank stride 4 -> 2-way (free)
#define SW_STRIDE 36        // pad 32->36: k-row bank stride 4 -> conflict-free
#define SS_STRIDE 132       // score rows: 4 waves * 32 cols, float4-aligned

__device__ __forceinline__ float softplus_f(float x) {
  // jax.nn.softplus = max(x,0) + log1p(exp(-|x|))
  return fmaxf(x, 0.0f) + log1pf(expf(-fabsf(x)));
}

__device__ __forceinline__ float get_comp(const float4& v, int kk) {
  return kk == 0 ? v.x : kk == 1 ? v.y : kk == 2 ? v.z : v.w;
}

__global__ __launch_bounds__(256, 4) void router_kernel(
    const float* __restrict__ mh, const float* __restrict__ dt,
    const float* __restrict__ dd, const float* __restrict__ rg,
    const float* __restrict__ de, const float* __restrict__ cemb_all,
    const float* __restrict__ w_route, const float* __restrict__ b_route,
    const float* __restrict__ w_noise, const float* __restrict__ b_noise,
    const float* __restrict__ eps, const int* __restrict__ city_index,
    float* __restrict__ out) {
  // smem union: [A 32x68 | W 64x36] (4480 floats) vs scores 32x132 (4224)
  __shared__ float smem[4480];
  __shared__ float city_l[32];
  float* sA = smem;          // [32][68]
  float* sW = smem + 2176;   // [64][36]
  float* sS = smem;          // [32][132] after final barrier

  const int tid = threadIdx.x;
  const int w   = tid >> 6;        // wave 0..3: k-quarter of each chunk
  const int ln  = tid & 63;
  const int tg  = ln & 7;          // tokens {tg, tg+8, tg+16, tg+24}
  const int eg  = ln >> 3;         // cols eg*4..eg*4+3 (of 32 = route|noise)
  const int blockTok = blockIdx.x * TOKS;

  // staging/prefetch coordinates (coalesced: 16 rows x 256B per instr)
  const int ar0 = tid >> 4,        ac0 = (tid & 15) * 4;          // A slot 0
  const int ar1 = (tid + 256) >> 4, ac1 = (tid & 15) * 4;         // A slot 1
  const int wr0 = tid >> 3,        wc0 = tid & 7;                 // W slot 0
  const int wr1 = (tid + 256) >> 3, wc1 = tid & 7;                // W slot 1

  // ---- constant: bias + city_embed . W[1024:1056] ----
  if (tid < 32) {
    const int e = tid & 15;
    const float* wsrc = (tid < 16) ? w_route : w_noise;
    const float* bsrc = (tid < 16) ? b_route : b_noise;
    const float* ce = cemb_all + city_index[0] * 32;
    float s = bsrc[e];
#pragma unroll
    for (int j = 0; j < 32; ++j) s = fmaf(ce[j], wsrc[(1024 + j) * 16 + e], s);
    city_l[tid] = s;
  }

  float4 acc0 = make_float4(0.f,0.f,0.f,0.f);
  float4 acc1 = make_float4(0.f,0.f,0.f,0.f);
  float4 acc2 = make_float4(0.f,0.f,0.f,0.f);
  float4 acc3 = make_float4(0.f,0.f,0.f,0.f);

  float4 Areg0, Areg1, Wreg0, Wreg1;  // named scalars: must stay in VGPRs

  auto a_src = [&](int g, int row) -> const float* {
    // 64-k chunk g -> source array + stride; boundaries all multiples of 64
    const float* base; int stride;
    if (g < 16)      { base = mh + g * 64;        stride = 1024; }
    else if (g < 20) { base = dt + (g - 16) * 64; stride = 256; }
    else if (g < 24) { base = dd + (g - 20) * 64; stride = 256; }
    else if (g < 26) { base = rg + (g - 24) * 64; stride = 128; }
    else             { base = de + (g - 26) * 64; stride = 128; }
    return base + (size_t)(blockTok + row) * stride;
  };

  auto prefetch = [&](int g) {
    Areg0 = *(const float4*)(a_src(g, ar0) + ac0);
    Areg1 = *(const float4*)(a_src(g, ar1) + ac1);
    const int kb = g * 64 + ((g * 64 >= 1024) ? 32 : 0);  // skip city rows
    const float* s0 = (wc0 < 4) ? (w_route + (kb + wr0) * 16 + wc0 * 4)
                                : (w_noise + (kb + wr0) * 16 + (wc0 - 4) * 4);
    const float* s1 = (wc1 < 4) ? (w_route + (kb + wr1) * 16 + wc1 * 4)
                                : (w_noise + (kb + wr1) * 16 + (wc1 - 4) * 4);
    Wreg0 = *(const float4*)s0;
    Wreg1 = *(const float4*)s1;
  };

  prefetch(0);

  for (int c = 0; c < NCHUNK; ++c) {
    __syncthreads();  // previous compute done -> LDS free
    *(float4*)&sA[ar0 * SA_STRIDE + ac0] = Areg0;
    *(float4*)&sA[ar1 * SA_STRIDE + ac1] = Areg1;
    *(float4*)&sW[wr0 * SW_STRIDE + wc0 * 4] = Wreg0;
    *(float4*)&sW[wr1 * SW_STRIDE + wc1 * 4] = Wreg1;
    __syncthreads();  // tile visible

    if (c + 1 < NCHUNK) prefetch(c + 1);  // in flight over compute

#pragma unroll
    for (int qq = 0; qq < 4; ++qq) {
      const int koff = w * 16 + qq * 4;   // this wave's k-quarter
      // A: 4 tokens x 4 k — 2-way bank (free), 8-lane broadcast
      float4 a0 = *(const float4*)&sA[(tg +  0) * SA_STRIDE + koff];
      float4 a1 = *(const float4*)&sA[(tg +  8) * SA_STRIDE + koff];
      float4 a2 = *(const float4*)&sA[(tg + 16) * SA_STRIDE + koff];
      float4 a3 = *(const float4*)&sA[(tg + 24) * SA_STRIDE + koff];
#pragma unroll
      for (int kk = 0; kk < 4; ++kk) {
        float4 wv = *(const float4*)&sW[(koff + kk) * SW_STRIDE + eg * 4];
        float s;
        s = get_comp(a0, kk);
        acc0.x = fmaf(s, wv.x, acc0.x); acc0.y = fmaf(s, wv.y, acc0.y);
        acc0.z = fmaf(s, wv.z, acc0.z); acc0.w = fmaf(s, wv.w, acc0.w);
        s = get_comp(a1, kk);
        acc1.x = fmaf(s, wv.x, acc1.x); acc1.y = fmaf(s, wv.y, acc1.y);
        acc1.z = fmaf(s, wv.z, acc1.z); acc1.w = fmaf(s, wv.w, acc1.w);
        s = get_comp(a2, kk);
        acc2.x = fmaf(s, wv.x, acc2.x); acc2.y = fmaf(s, wv.y, acc2.y);
        acc2.z = fmaf(s, wv.z, acc2.z); acc2.w = fmaf(s, wv.w, acc2.w);
        s = get_comp(a3, kk);
        acc3.x = fmaf(s, wv.x, acc3.x); acc3.y = fmaf(s, wv.y, acc3.y);
        acc3.z = fmaf(s, wv.z, acc3.z); acc3.w = fmaf(s, wv.w, acc3.w);
      }
    }
  }

  // ---- split-K reduction through LDS ----
  __syncthreads();  // all waves done with sA/sW; smem becomes scores[32][132]
  {
    float* s0 = &sS[(tg +  0) * SS_STRIDE + w * 32 + eg * 4];
    float* s1 = &sS[(tg +  8) * SS_STRIDE + w * 32 + eg * 4];
    float* s2 = &sS[(tg + 16) * SS_STRIDE + w * 32 + eg * 4];
    float* s3 = &sS[(tg + 24) * SS_STRIDE + w * 32 + eg * 4];
    *(float4*)s0 = acc0; *(float4*)s1 = acc1;
    *(float4*)s2 = acc2; *(float4*)s3 = acc3;
  }
  __syncthreads();

  // ---- epilogue: one lane per token ----
  if (tid < TOKS) {
    const int tokg = blockTok + tid;
    float l[32];
#pragma unroll
    for (int e4 = 0; e4 < 8; ++e4) {
      float4 s0 = *(const float4*)&sS[tid * SS_STRIDE +  0 + e4 * 4];
      float4 s1 = *(const float4*)&sS[tid * SS_STRIDE + 32 + e4 * 4];
      float4 s2 = *(const float4*)&sS[tid * SS_STRIDE + 64 + e4 * 4];
      float4 s3 = *(const float4*)&sS[tid * SS_STRIDE + 96 + e4 * 4];
      l[e4 * 4 + 0] = s0.x + s1.x + s2.x + s3.x + city_l[e4 * 4 + 0];
      l[e4 * 4 + 1] = s0.y + s1.y + s2.y + s3.y + city_l[e4 * 4 + 1];
      l[e4 * 4 + 2] = s0.z + s1.z + s2.z + s3.z + city_l[e4 * 4 + 2];
      l[e4 * 4 + 3] = s0.w + s1.w + s2.w + s3.w + city_l[e4 * 4 + 3];
    }

    const float* ep = eps + (size_t)tokg * 16;
    float n[16];
#pragma unroll
    for (int e = 0; e < 16; ++e)
      n[e] = fmaf(ep[e], softplus_f(l[16 + e]), l[e]);

    // top-2, lowest-index tie-break (matches lax.top_k)
    float m1 = -INFINITY; int i1 = 0;
#pragma unroll
    for (int e = 0; e < 16; ++e)
      if (n[e] > m1) { m1 = n[e]; i1 = e; }
    float m2 = -INFINITY; int i2 = 0;
#pragma unroll
    for (int e = 0; e < 16; ++e)
      if (e != i1 && n[e] > m2) { m2 = n[e]; i2 = e; }

    float ex[16], Z = 0.f;
#pragma unroll
    for (int e = 0; e < 16; ++e) { ex[e] = expf(n[e] - m1); Z += ex[e]; }
    const float invZ  = 1.0f / Z;
    const float invZ2 = 1.0f / (1.0f + expf(m2 - m1));  // ex[i1]=1

    float r[16], g1[16];
#pragma unroll
    for (int e = 0; e < 16; ++e) {
      r[e]  = (e == i1 || e == i2) ? ex[e] * invZ2 : 0.0f;
      g1[e] = ex[e] * invZ;
    }

    float* ro = out + (size_t)tokg * 16;
#pragma unroll
    for (int e4 = 0; e4 < 4; ++e4)
      *(float4*)(ro + e4 * 4) = make_float4(r[e4*4], r[e4*4+1], r[e4*4+2], r[e4*4+3]);

    out[I_OFF + (size_t)tokg * 2 + 0] = (float)i1;
    out[I_OFF + (size_t)tokg * 2 + 1] = (float)i2;

    float* go = out + G_OFF + (size_t)tokg * 16;
#pragma unroll
    for (int e4 = 0; e4 < 4; ++e4)
      *(float4*)(go + e4 * 4) = make_float4(g1[e4*4], g1[e4*4+1], g1[e4*4+2], g1[e4*4+3]);
  }
}

extern "C" void kernel_launch(void* const* d_in, const int* in_sizes, int n_in,
                              void* d_out, int out_size, void* d_ws, size_t ws_size,
                              hipStream_t stream) {
  const float* mh = (const float*)d_in[0];   // [8,4096,1024]
  const float* dt = (const float*)d_in[1];   // [8,4096,256]
  const float* dd = (const float*)d_in[2];   // [8,4096,256]
  const float* rg = (const float*)d_in[3];   // [8,4096,128]
  const float* de = (const float*)d_in[4];   // [8,4096,128]
  const float* ce = (const float*)d_in[5];   // [4,32]
  const float* wr = (const float*)d_in[6];   // [1824,16]
  const float* br = (const float*)d_in[7];   // [16]
  const float* wn = (const float*)d_in[8];   // [1824,16]
  const float* bn = (const float*)d_in[9];   // [16]
  const float* ep = (const float*)d_in[10];  // [8,4096,16]
  const int*   ci = (const int*)d_in[11];    // scalar
  float* out = (float*)d_out;

  router_kernel<<<1024, 256, 0, stream>>>(mh, dt, dd, rg, de, ce, wr, br, wn, bn,
                                          ep, ci, out);
}